// Round 16
// baseline (415.562 us; speedup 1.0000x reference)
//
#include <hip/hip_runtime.h>
#include <hip/hip_bf16.h>
#include <math.h>
#include <utility>

#define C 21
#define H 512
#define W 512
#define HW (H*W)
#define CHW (C*HW)
#define N_ITERS 5
#define RSP 6
#define KSP 13
#define RBI 8
#define KBI 17
#define LIST_CAP 4096

// workspace layout (float offsets)
#define KSP_OFF   0
#define KBI_OFF   16
#define NSP_OFF   64      // stores 1/nsp
#define NBI_OFF   576     // stores 1/nbi
#define M1_OFF    1088
#define M2_OFF    1536
#define NCOND_OFF 2048    // N_ITERS ints
#define S1_OFF    2064    // N_ITERS*C
#define S2_OFF    2176    // N_ITERS*C
#define CTR_OFF   2288    // N_ITERS ints (spin-barrier counters)
#define LIST_OFF  2304    // N_ITERS*LIST_CAP ints -> ends 22784
#define CONTB_OFF 22784   // LIST_CAP*C floats -> ends 108800
#define UBH_OFF   131072                  // CHW bf16 = CHW/2 floats
#define QB16_OFF  (UBH_OFF + CHW/2)       // CHW bf16 (q iterate)
#define T12_OFF   (QB16_OFF + CHW/2)      // CHW dwords (bf16 t1 | t2<<16)

#define REP21(F) F(0) F(1) F(2) F(3) F(4) F(5) F(6) F(7) F(8) F(9) F(10) \
                 F(11) F(12) F(13) F(14) F(15) F(16) F(17) F(18) F(19) F(20)

template <int... Js, typename F>
__device__ __forceinline__ void sfor(std::integer_sequence<int, Js...>, F&& f) {
  (f(std::integral_constant<int, Js>{}), ...);
}
#define SFOR(N, ...) sfor(std::make_integer_sequence<int, N>{}, __VA_ARGS__)

__device__ __forceinline__ float bf2f(unsigned short u) {
  return __uint_as_float(((unsigned)u) << 16);
}
__device__ __forceinline__ unsigned short f2bfu(float a) {
  __hip_bfloat16 h = __float2bfloat16(a);
  return *(unsigned short*)&h;
}
__device__ __forceinline__ unsigned packbf(float a, float b) {
  return (unsigned)f2bfu(a) | ((unsigned)f2bfu(b) << 16);
}

__global__ __launch_bounds__(512) void k_setup(float* ws, const float* skw,
                                               const float* bkw, const float* cm) {
  int tid = threadIdx.x;
  if (tid == 0) {
    float s = 0.f;
    for (int i = 0; i < KSP; ++i) {
      float t = (float)(i - RSP);
      float v = expf(-0.5f * (t / 3.0f) * (t / 3.0f));
      ws[KSP_OFF + i] = v; s += v;
    }
    for (int i = 0; i < KSP; ++i) ws[KSP_OFF + i] /= s;
    s = 0.f;
    for (int i = 0; i < KBI; ++i) {
      float t = (float)(i - RBI);
      float v = expf(-0.5f * (t / 160.0f) * (t / 160.0f));
      ws[KBI_OFF + i] = v; s += v;
    }
    for (int i = 0; i < KBI; ++i) ws[KBI_OFF + i] /= s;
  }
  __syncthreads();
  if (tid < H) {
    float nsp = 0.f, nbi = 0.f;
    for (int t = 0; t < KSP; ++t) { int x = tid + t - RSP; if (x >= 0 && x < H) nsp += ws[KSP_OFF + t]; }
    for (int t = 0; t < KBI; ++t) { int x = tid + t - RBI; if (x >= 0 && x < H) nbi += ws[KBI_OFF + t]; }
    ws[NSP_OFF + tid] = 1.f / nsp;
    ws[NBI_OFF + tid] = 1.f / nbi;
  }
  if (tid < C * C) {
    int i = tid / C, j = tid % C;
    float m1 = 0.f, m2 = 0.f;
    for (int k = 0; k < C; ++k) {
      m1 += cm[i * C + k] * skw[k * C + j];
      m2 += cm[i * C + k] * bkw[k * C + j];
    }
    ws[M1_OFF + tid] = m1;
    ws[M2_OFF + tid] = m2;
  }
  if (tid < N_ITERS * C) { ws[S1_OFF + tid] = 0.f; ws[S2_OFF + tid] = 0.f; }
  if (tid < N_ITERS) {
    ((int*)(ws + NCOND_OFF))[tid] = 0;
    ((int*)(ws + CTR_OFF))[tid] = 0;
  }
}

// merged: compact per-sp_id pixel lists (coalesced sp_map read) +
// (H,W,C)f32 -> (C,H,W)bf16 u shadow (q0 aliases ubh; no qb init needed)
__global__ __launch_bounds__(256) void k_spt_tin(const int* __restrict__ sp_map,
                                                 const float* __restrict__ in,
                                                 int* __restrict__ ncond,
                                                 int* __restrict__ list,
                                                 unsigned* __restrict__ ubh32) {
  __shared__ float t[C * 257];
  int tid = threadIdx.x;
  {
    int m = blockIdx.x * 256 + tid;      // coalesced index into sp_map (W,H)
    int v = sp_map[m];
    int p = ((m & 511) << 9) | (m >> 9); // pixel index in (H,W) space
#pragma unroll
    for (int i = 0; i < N_ITERS; ++i)
      if (v == 250 + 7 * i) {
        int slot = atomicAdd(&ncond[i], 1);
        if (slot < LIST_CAP) list[i * LIST_CAP + slot] = p;
      }
  }
  size_t p0 = (size_t)blockIdx.x * 256;
  size_t fbase = p0 * C;
#pragma unroll
  for (int i = 0; i < C; ++i) {
    int e = i * 256 + tid;
    int pp = e / C, c = e % C;
    t[c * 257 + pp] = in[fbase + e];
  }
  __syncthreads();
  // full-width phase 2: all 256 threads, C*128 = 2688 dword stores
  for (int e = tid; e < C * 128; e += 256) {
    int c = e >> 7, pr = e & 127;
    float v0 = t[c * 257 + 2 * pr];
    float v1 = t[c * 257 + 2 * pr + 1];
    ubh32[((size_t)c * HW + p0) / 2 + pr] = packbf(v0, v1);
  }
}

// final transpose: (C,H,W) bf16 q -> (H,W,C) f32 out
__global__ __launch_bounds__(256) void k_tout(const unsigned* __restrict__ qb32,
                                              float* __restrict__ out) {
  __shared__ float t[C * 257];
  int tid = threadIdx.x;
  size_t p0 = (size_t)blockIdx.x * 256;
  if (tid < 128) {
#pragma unroll
    for (int c = 0; c < C; ++c) {
      unsigned d = qb32[((size_t)c * HW + p0) / 2 + tid];
      t[c * 257 + 2 * tid] = __uint_as_float(d << 16);
      t[c * 257 + 2 * tid + 1] = __uint_as_float(d & 0xFFFF0000u);
    }
  }
  __syncthreads();
  size_t fbase = p0 * C;
#pragma unroll
  for (int i = 0; i < C; ++i) {
    int e = i * 256 + tid;
    int p = e / C, c = e % C;
    out[fbase + e] = t[c * 257 + p];
  }
}

// fused clique: phase 0 (apply PREVIOUS iter's contfix patches; disjoint
// pixel sets, no race) -> pass A (partial sums -> global S1/S2) ->
// 4-block spin barrier -> pass B (per-cond-pixel cont into contb).
__global__ __launch_bounds__(256) void k_clique(unsigned short* __restrict__ qh,
                                                float* __restrict__ ws,
                                                const float* __restrict__ loww,
                                                const float* __restrict__ highw,
                                                int iter) {
  int tid = threadIdx.x;
  const int* ncond = (const int*)(ws + NCOND_OFF);
  const int* list = (const int*)(ws + LIST_OFF) + iter * LIST_CAP;
  int n = ncond[iter]; if (n > LIST_CAP) n = LIST_CAP;
  float high0 = highw[0], high1 = highw[1];
  float cc = high0 + high1;
  if (iter > 0) {
    int np = ncond[iter - 1]; if (np > LIST_CAP) np = LIST_CAP;
    const int* plist = (const int*)(ws + LIST_OFF) + (iter - 1) * LIST_CAP;
    for (int e = blockIdx.x * 256 + tid; e < np * C; e += 1024) {
      int j = e / C, c = e - j * C;
      int p = plist[j];
      size_t idx = (size_t)c * HW + p;
      qh[idx] = f2bfu(bf2f(qh[idx]) + cc - ws[CONTB_OFF + e]);
    }
  }
#define D1(i) float s1_##i = 0.f, s2_##i = 0.f;
  REP21(D1)
#undef D1
  for (int j = blockIdx.x * 256 + tid; j < n; j += 1024) {
    int p = list[j];
#define LQ(i) float q##i = __expf(bf2f(qh[(size_t)(i) * HW + p]));
    REP21(LQ)
#undef LQ
    float s = ((((q0+q1)+(q2+q3))+((q4+q5)+(q6+q7)))+(((q8+q9)+(q10+q11))+((q12+q13)+(q14+q15))))+(((q16+q17)+(q18+q19))+q20);
    float inv = 1.f / s;
    float smax = 0.f;
#define NM(i) q##i *= inv; smax = fmaxf(smax, q##i);
    REP21(NM)
#undef NM
#define AC(i) { s1_##i += __expf(q##i); \
                float A = (q##i == smax) ? smax : q##i + smax; \
                s2_##i += __expf(A); }
    REP21(AC)
#undef AC
  }
#define RED(x) x += __shfl_xor(x, 32); x += __shfl_xor(x, 16); x += __shfl_xor(x, 8); \
               x += __shfl_xor(x, 4); x += __shfl_xor(x, 2); x += __shfl_xor(x, 1);
#define RD(i) RED(s1_##i) RED(s2_##i)
  REP21(RD)
#undef RD
#undef RED
  if ((tid & 63) == 0) {
#define AT(i) atomicAdd(&ws[S1_OFF + iter * C + (i)], s1_##i); \
              atomicAdd(&ws[S2_OFF + iter * C + (i)], s2_##i);
    REP21(AT)
#undef AT
  }
  // 4-block barrier: device-scope counter spin
  __threadfence();
  __syncthreads();
  if (tid == 0) {
    int* ctr = (int*)(ws + CTR_OFF) + iter;
    atomicAdd(ctr, 1);
    while (atomicAdd(ctr, 0) < 4) { __builtin_amdgcn_s_sleep(1); }
  }
  __syncthreads();
  __threadfence();
  float HWn = (float)(HW - n);
#define LB(i) float lb1_##i = logf(HWn + ws[S1_OFF + iter * C + (i)]); \
              float lb2_##i = logf(HWn + ws[S2_OFF + iter * C + (i)]);
  REP21(LB)
#undef LB
  float* contb = ws + CONTB_OFF;
  for (int j = blockIdx.x * 256 + tid; j < n; j += 1024) {
    int p = list[j];
#define LQ2(i) float q##i = __expf(bf2f(qh[(size_t)(i) * HW + p]));
    REP21(LQ2)
#undef LQ2
    float s = ((((q0+q1)+(q2+q3))+((q4+q5)+(q6+q7)))+(((q8+q9)+(q10+q11))+((q12+q13)+(q14+q15))))+(((q16+q17)+(q18+q19))+q20);
    float inv = 1.f / s;
    float smax = 0.f;
#define NM2(i) q##i *= inv; smax = fmaxf(smax, q##i);
    REP21(NM2)
#undef NM2
#define CW(i) { float A = (q##i == smax) ? smax : q##i + smax; \
                float ft = lb1_##i / q##i; \
                float ft2 = lb2_##i / A; \
                contb[j * C + (i)] = loww[i] * ft + high0 * (1.f - ft) \
                                   + loww[C + (i)] * ft2 + high1 * (1.f - ft2); }
    REP21(CW)
#undef CW
  }
}

// softmax + channel-mix: bf16-pair q in, interleaved (t1|t2<<16) out.
__global__ __launch_bounds__(256) void k_smmix(const unsigned* __restrict__ q16x2,
                                               unsigned* __restrict__ t12,
                                               const float* __restrict__ ws) {
  int tid = threadIdx.x;
  int b2 = blockIdx.x * 256 + tid;   // pair index within channel
#define LQ(i) unsigned d##i = q16x2[(size_t)(i) * (HW/2) + b2]; \
              float ex##i = __expf(__uint_as_float(d##i << 16)); \
              float ey##i = __expf(__uint_as_float(d##i & 0xFFFF0000u));
  REP21(LQ)
#undef LQ
  float sa = ((((ex0+ex1)+(ex2+ex3))+((ex4+ex5)+(ex6+ex7)))+(((ex8+ex9)+(ex10+ex11))+((ex12+ex13)+(ex14+ex15))))+(((ex16+ex17)+(ex18+ex19))+ex20);
  float sb = ((((ey0+ey1)+(ey2+ey3))+((ey4+ey5)+(ey6+ey7)))+(((ey8+ey9)+(ey10+ey11))+((ey12+ey13)+(ey14+ey15))))+(((ey16+ey17)+(ey18+ey19))+ey20);
  float ia = 1.f / sa, ib = 1.f / sb;
#define NQ(i) ex##i *= ia; ey##i *= ib;
  REP21(NQ)
#undef NQ
  for (int i = 0; i < C; ++i) {
    const float* r1 = ws + M1_OFF + i * C;
    const float* r2 = ws + M2_OFF + i * C;
    float t1a = 0.f, t1b = 0.f, t2a = 0.f, t2b = 0.f;
#define MIX(c) { float m1v = r1[c], m2v = r2[c]; \
                 t1a += m1v * ex##c; t1b += m1v * ey##c; \
                 t2a += m2v * ex##c; t2b += m2v * ey##c; }
    REP21(MIX)
#undef MIX
    uint2 st;
    st.x = packbf(t1a, t2a);
    st.y = packbf(t1b, t2b);
    *reinterpret_cast<uint2*>(t12 + (size_t)i * HW + 2 * b2) = st;
  }
}

// fused 2D blur + norm + q-update. 128x16 tile, interleaved bf16 pair loads.
// Always writes packed bf16 q (C,H,W) via coalesced uint2 stores.
__global__ __launch_bounds__(256) void k_blur2d(
    const unsigned* __restrict__ t12, const unsigned* __restrict__ uh32,
    unsigned* __restrict__ qout, const float* __restrict__ ws,
    const float* __restrict__ highw) {
  __shared__ float asmem[16 * 152], bsmem[16 * 152];
  __shared__ float ktsp[KSP], ktbi[KBI];
  __shared__ float nspw[128], nbiw[128], nsph[16], nbih[16];
  int tid = threadIdx.x;
  // bijective XCD-chunk swizzle: 2688 blocks = 8 * 336
  int l = blockIdx.x;
  int nl = (l & 7) * 336 + (l >> 3);
  int c = nl >> 7;                 // 128 tiles per channel
  int rem = nl & 127;
  int h0 = (rem >> 2) * 16;
  int w0 = (rem & 3) * 128;
  if (tid < KSP) ktsp[tid] = ws[KSP_OFF + tid];
  if (tid >= 32 && tid < 32 + KBI) ktbi[tid - 32] = ws[KBI_OFF + tid - 32];
  if (tid >= 64 && tid < 192) {
    int i = tid - 64;
    nspw[i] = ws[NSP_OFF + w0 + i];
    nbiw[i] = ws[NBI_OFF + w0 + i];
  }
  if (tid >= 192 && tid < 208) {
    int i = tid - 192;
    nsph[i] = ws[NSP_OFF + h0 + i];
    nbih[i] = ws[NBI_OFF + h0 + i];
  }
  __syncthreads();
  size_t cbase = (size_t)c * HW;
  if (tid < 144) {
    int col = w0 - 8 + tid;
    bool okc = (col >= 0 && col < W);
    const unsigned* s12 = t12 + cbase;
    unsigned lv[32];
    SFOR(32, [&](auto jc) {
      constexpr int j = decltype(jc)::value;
      int hh = h0 - 8 + j;
      lv[j] = (okc && hh >= 0 && hh < H) ? s12[(size_t)hh * W + col] : 0u;
    });
    float a[16], b[16];
    SFOR(16, [&](auto oc) {
      constexpr int o = decltype(oc)::value;
      a[o] = 0.f; b[o] = 0.f;
    });
    SFOR(32, [&](auto jc) {
      constexpr int j = decltype(jc)::value;
      float f1 = __uint_as_float(lv[j] << 16);
      float f2 = __uint_as_float(lv[j] & 0xFFFF0000u);
      SFOR(16, [&](auto oc) {
        constexpr int o = decltype(oc)::value;
        if constexpr (j - 2 - o >= 0 && j - 2 - o < KSP) a[o] += ktsp[j - 2 - o] * f1;
        if constexpr (j - o >= 0 && j - o < KBI) b[o] += ktbi[j - o] * f2;
      });
    });
    SFOR(16, [&](auto oc) {
      constexpr int o = decltype(oc)::value;
      asmem[o * 152 + tid] = a[o];
      bsmem[o * 152 + tid] = b[o];
    });
  }
  __syncthreads();
  float cc = highw[0] + highw[1];
#pragma unroll
  for (int k = 0; k < 2; ++k) {
    int o = tid + k * 256;          // quad index, 512 quads (4 outputs each)
    int r = o >> 5;                 // 32 quads per row
    int wq = (o & 31) * 4;          // start col within tile (mult of 4)
    float aw[16], bw[20];
    const float2* ap = reinterpret_cast<const float2*>(&asmem[r * 152 + wq + 2]);
    const float2* bp = reinterpret_cast<const float2*>(&bsmem[r * 152 + wq]);
    SFOR(8, [&](auto jc) {
      constexpr int j = decltype(jc)::value;
      float2 v = ap[j];
      aw[2 * j] = v.x;
      aw[2 * j + 1] = v.y;
    });
    SFOR(10, [&](auto jc) {
      constexpr int j = decltype(jc)::value;
      float2 v = bp[j];
      bw[2 * j] = v.x;
      bw[2 * j + 1] = v.y;
    });
    float ao[4], bo[4];
    SFOR(4, [&](auto jc) {
      constexpr int j = decltype(jc)::value;
      float s1 = 0.f;
      float s2 = 0.f;
      SFOR(KSP, [&](auto tc) {
        constexpr int t = decltype(tc)::value;
        s1 += ktsp[t] * aw[j + t];
      });
      SFOR(KBI, [&](auto tc) {
        constexpr int t = decltype(tc)::value;
        s2 += ktbi[t] * bw[j + t];
      });
      ao[j] = s1;
      bo[j] = s2;
    });
    int hh = h0 + r, ww = w0 + wq;
    size_t idx = cbase + (size_t)hh * W + ww;
    uint2 uv = *reinterpret_cast<const uint2*>(uh32 + (idx >> 1));
    float u0 = __uint_as_float(uv.x << 16);
    float u1 = __uint_as_float(uv.x & 0xFFFF0000u);
    float u2 = __uint_as_float(uv.y << 16);
    float u3 = __uint_as_float(uv.y & 0xFFFF0000u);
    float nh1 = nsph[r], nh2 = nbih[r];
    float r0 = u0 - (ao[0] * (nh1 * nspw[wq])     + bo[0] * (nh2 * nbiw[wq]))     - cc;
    float r1 = u1 - (ao[1] * (nh1 * nspw[wq + 1]) + bo[1] * (nh2 * nbiw[wq + 1])) - cc;
    float r2 = u2 - (ao[2] * (nh1 * nspw[wq + 2]) + bo[2] * (nh2 * nbiw[wq + 2])) - cc;
    float r3 = u3 - (ao[3] * (nh1 * nspw[wq + 3]) + bo[3] * (nh2 * nbiw[wq + 3])) - cc;
    uint2 st;
    st.x = packbf(r0, r1);
    st.y = packbf(r2, r3);
    *reinterpret_cast<uint2*>(qout + (idx >> 1)) = st;
  }
}

// patch cond pixels in bf16 q: q += cc - cont (final iteration only)
__global__ __launch_bounds__(256) void k_contfix(unsigned short* __restrict__ q16,
                                                 const float* __restrict__ ws,
                                                 const float* __restrict__ highw,
                                                 int iter) {
  const int* ncond = (const int*)(ws + NCOND_OFF);
  int n = ncond[iter]; if (n > LIST_CAP) n = LIST_CAP;
  int e = blockIdx.x * 256 + threadIdx.x;
  if (e >= n * C) return;
  int j = e / C, c = e - j * C;
  const int* list = (const int*)(ws + LIST_OFF) + iter * LIST_CAP;
  int p = list[j];
  float cc = highw[0] + highw[1];
  float delta = cc - ws[CONTB_OFF + e];
  size_t idx = (size_t)c * HW + p;
  q16[idx] = f2bfu(bf2f(q16[idx]) + delta);
}

extern "C" void kernel_launch(void* const* d_in, const int* in_sizes, int n_in,
                              void* d_out, int out_size, void* d_ws, size_t ws_size,
                              hipStream_t stream) {
  const float* unaries = (const float*)d_in[0];
  const int* sp_map = (const int*)d_in[2];
  const float* skw = (const float*)d_in[3];
  const float* bkw = (const float*)d_in[4];
  const float* loww = (const float*)d_in[5];
  const float* highw = (const float*)d_in[6];
  const float* cm = (const float*)d_in[7];
  float* out = (float*)d_out;
  float* ws = (float*)d_ws;
  unsigned* ubh32 = (unsigned*)(ws + UBH_OFF);
  unsigned* qb32 = (unsigned*)(ws + QB16_OFF);
  unsigned short* qh16 = (unsigned short*)(ws + QB16_OFF);
  unsigned short* uh16 = (unsigned short*)(ws + UBH_OFF);
  unsigned* t12 = (unsigned*)(ws + T12_OFF);
  int* ncond = (int*)(ws + NCOND_OFF);
  int* list = (int*)(ws + LIST_OFF);

  k_setup<<<1, 512, 0, stream>>>(ws, skw, bkw, cm);
  k_spt_tin<<<HW / 256, 256, 0, stream>>>(sp_map, unaries, ncond, list, ubh32);
  for (int i = 0; i < N_ITERS; ++i) {
    // iter 0 reads ubh directly (q0 == bf16(u)); patches (iter>0) always
    // target qb which is also the read buffer then.
    unsigned short* qcur16 = (i == 0) ? uh16 : qh16;
    const unsigned* qcur32 = (i == 0) ? ubh32 : qb32;
    k_clique<<<4, 256, 0, stream>>>(qcur16, ws, loww, highw, i);
    k_smmix<<<HW / 512, 256, 0, stream>>>(qcur32, t12, ws);
    k_blur2d<<<2688, 256, 0, stream>>>(t12, ubh32, qb32, ws, highw);
  }
  k_contfix<<<128, 256, 0, stream>>>(qh16, ws, highw, N_ITERS - 1);
  k_tout<<<HW / 256, 256, 0, stream>>>(qb32, out);
}

// Round 17
// 372.334 us; speedup vs baseline: 1.1161x; 1.1161x over previous
//
#include <hip/hip_runtime.h>
#include <hip/hip_bf16.h>
#include <math.h>
#include <utility>

#define C 21
#define H 512
#define W 512
#define HW (H*W)
#define CHW (C*HW)
#define N_ITERS 5
#define RSP 6
#define KSP 13
#define RBI 8
#define KBI 17
#define LIST_CAP 4096

// workspace layout (float offsets)
#define KSP_OFF   0
#define KBI_OFF   16
#define NSP_OFF   64      // stores 1/nsp
#define NBI_OFF   576     // stores 1/nbi
#define M1_OFF    1088
#define M2_OFF    1536
#define NCOND_OFF 2048    // N_ITERS ints
#define S1_OFF    2064    // N_ITERS*C
#define S2_OFF    2176    // N_ITERS*C
#define CTR_OFF   2288    // N_ITERS ints (spin-barrier counters)
#define LIST_OFF  2304    // N_ITERS*LIST_CAP ints -> ends 22784
#define CONTB_OFF 22784   // LIST_CAP*C floats -> ends 108800
#define UBH_OFF   131072                  // CHW bf16 = CHW/2 floats
#define QB16_OFF  (UBH_OFF + CHW/2)       // CHW bf16 (q iterate)
#define T12_OFF   (QB16_OFF + CHW/2)      // CHW dwords (bf16 t1 | t2<<16)

#define REP21(F) F(0) F(1) F(2) F(3) F(4) F(5) F(6) F(7) F(8) F(9) F(10) \
                 F(11) F(12) F(13) F(14) F(15) F(16) F(17) F(18) F(19) F(20)

template <int... Js, typename F>
__device__ __forceinline__ void sfor(std::integer_sequence<int, Js...>, F&& f) {
  (f(std::integral_constant<int, Js>{}), ...);
}
#define SFOR(N, ...) sfor(std::make_integer_sequence<int, N>{}, __VA_ARGS__)

__device__ __forceinline__ float bf2f(unsigned short u) {
  return __uint_as_float(((unsigned)u) << 16);
}
__device__ __forceinline__ unsigned short f2bfu(float a) {
  __hip_bfloat16 h = __float2bfloat16(a);
  return *(unsigned short*)&h;
}
__device__ __forceinline__ unsigned packbf(float a, float b) {
  return (unsigned)f2bfu(a) | ((unsigned)f2bfu(b) << 16);
}

__global__ __launch_bounds__(512) void k_setup(float* ws, const float* skw,
                                               const float* bkw, const float* cm) {
  int tid = threadIdx.x;
  if (tid == 0) {
    float s = 0.f;
    for (int i = 0; i < KSP; ++i) {
      float t = (float)(i - RSP);
      float v = expf(-0.5f * (t / 3.0f) * (t / 3.0f));
      ws[KSP_OFF + i] = v; s += v;
    }
    for (int i = 0; i < KSP; ++i) ws[KSP_OFF + i] /= s;
    s = 0.f;
    for (int i = 0; i < KBI; ++i) {
      float t = (float)(i - RBI);
      float v = expf(-0.5f * (t / 160.0f) * (t / 160.0f));
      ws[KBI_OFF + i] = v; s += v;
    }
    for (int i = 0; i < KBI; ++i) ws[KBI_OFF + i] /= s;
  }
  __syncthreads();
  if (tid < H) {
    float nsp = 0.f, nbi = 0.f;
    for (int t = 0; t < KSP; ++t) { int x = tid + t - RSP; if (x >= 0 && x < H) nsp += ws[KSP_OFF + t]; }
    for (int t = 0; t < KBI; ++t) { int x = tid + t - RBI; if (x >= 0 && x < H) nbi += ws[KBI_OFF + t]; }
    ws[NSP_OFF + tid] = 1.f / nsp;
    ws[NBI_OFF + tid] = 1.f / nbi;
  }
  if (tid < C * C) {
    int i = tid / C, j = tid % C;
    float m1 = 0.f, m2 = 0.f;
    for (int k = 0; k < C; ++k) {
      m1 += cm[i * C + k] * skw[k * C + j];
      m2 += cm[i * C + k] * bkw[k * C + j];
    }
    ws[M1_OFF + tid] = m1;
    ws[M2_OFF + tid] = m2;
  }
  if (tid < N_ITERS * C) { ws[S1_OFF + tid] = 0.f; ws[S2_OFF + tid] = 0.f; }
  if (tid < N_ITERS) {
    ((int*)(ws + NCOND_OFF))[tid] = 0;
    ((int*)(ws + CTR_OFF))[tid] = 0;
  }
}

// merged: compact per-sp_id pixel lists (coalesced sp_map read) +
// (H,W,C)f32 -> (C,H,W)bf16 u shadow (q0 aliases ubh; no qb init needed)
__global__ __launch_bounds__(256) void k_spt_tin(const int* __restrict__ sp_map,
                                                 const float* __restrict__ in,
                                                 int* __restrict__ ncond,
                                                 int* __restrict__ list,
                                                 unsigned* __restrict__ ubh32) {
  __shared__ float t[C * 257];
  int tid = threadIdx.x;
  {
    int m = blockIdx.x * 256 + tid;      // coalesced index into sp_map (W,H)
    int v = sp_map[m];
    int p = ((m & 511) << 9) | (m >> 9); // pixel index in (H,W) space
#pragma unroll
    for (int i = 0; i < N_ITERS; ++i)
      if (v == 250 + 7 * i) {
        int slot = atomicAdd(&ncond[i], 1);
        if (slot < LIST_CAP) list[i * LIST_CAP + slot] = p;
      }
  }
  size_t p0 = (size_t)blockIdx.x * 256;
  size_t fbase = p0 * C;
#pragma unroll
  for (int i = 0; i < C; ++i) {
    int e = i * 256 + tid;
    int pp = e / C, c = e % C;
    t[c * 257 + pp] = in[fbase + e];
  }
  __syncthreads();
  // full-width phase 2: all 256 threads, C*128 = 2688 dword stores
  for (int e = tid; e < C * 128; e += 256) {
    int c = e >> 7, pr = e & 127;
    float v0 = t[c * 257 + 2 * pr];
    float v1 = t[c * 257 + 2 * pr + 1];
    ubh32[((size_t)c * HW + p0) / 2 + pr] = packbf(v0, v1);
  }
}

// final transpose: (C,H,W) bf16 q -> (H,W,C) f32 out
__global__ __launch_bounds__(256) void k_tout(const unsigned* __restrict__ qb32,
                                              float* __restrict__ out) {
  __shared__ float t[C * 257];
  int tid = threadIdx.x;
  size_t p0 = (size_t)blockIdx.x * 256;
  if (tid < 128) {
#pragma unroll
    for (int c = 0; c < C; ++c) {
      unsigned d = qb32[((size_t)c * HW + p0) / 2 + tid];
      t[c * 257 + 2 * tid] = __uint_as_float(d << 16);
      t[c * 257 + 2 * tid + 1] = __uint_as_float(d & 0xFFFF0000u);
    }
  }
  __syncthreads();
  size_t fbase = p0 * C;
#pragma unroll
  for (int i = 0; i < C; ++i) {
    int e = i * 256 + tid;
    int p = e / C, c = e % C;
    out[fbase + e] = t[c * 257 + p];
  }
}

// fused clique (read-only on q): pass A (partial sums -> global S1/S2) ->
// 4-block spin barrier -> pass B (per-cond-pixel cont into contb).
__global__ __launch_bounds__(256) void k_clique(const unsigned short* __restrict__ qh,
                                                float* __restrict__ ws,
                                                const float* __restrict__ loww,
                                                const float* __restrict__ highw,
                                                int iter) {
  int tid = threadIdx.x;
  const int* ncond = (const int*)(ws + NCOND_OFF);
  const int* list = (const int*)(ws + LIST_OFF) + iter * LIST_CAP;
  int n = ncond[iter]; if (n > LIST_CAP) n = LIST_CAP;
  float high0 = highw[0], high1 = highw[1];
#define D1(i) float s1_##i = 0.f, s2_##i = 0.f;
  REP21(D1)
#undef D1
  for (int j = blockIdx.x * 256 + tid; j < n; j += 1024) {
    int p = list[j];
#define LQ(i) float q##i = __expf(bf2f(qh[(size_t)(i) * HW + p]));
    REP21(LQ)
#undef LQ
    float s = ((((q0+q1)+(q2+q3))+((q4+q5)+(q6+q7)))+(((q8+q9)+(q10+q11))+((q12+q13)+(q14+q15))))+(((q16+q17)+(q18+q19))+q20);
    float inv = 1.f / s;
    float smax = 0.f;
#define NM(i) q##i *= inv; smax = fmaxf(smax, q##i);
    REP21(NM)
#undef NM
#define AC(i) { s1_##i += __expf(q##i); \
                float A = (q##i == smax) ? smax : q##i + smax; \
                s2_##i += __expf(A); }
    REP21(AC)
#undef AC
  }
#define RED(x) x += __shfl_xor(x, 32); x += __shfl_xor(x, 16); x += __shfl_xor(x, 8); \
               x += __shfl_xor(x, 4); x += __shfl_xor(x, 2); x += __shfl_xor(x, 1);
#define RD(i) RED(s1_##i) RED(s2_##i)
  REP21(RD)
#undef RD
#undef RED
  if ((tid & 63) == 0) {
#define AT(i) atomicAdd(&ws[S1_OFF + iter * C + (i)], s1_##i); \
              atomicAdd(&ws[S2_OFF + iter * C + (i)], s2_##i);
    REP21(AT)
#undef AT
  }
  // 4-block barrier: device-scope counter spin
  __threadfence();
  __syncthreads();
  if (tid == 0) {
    int* ctr = (int*)(ws + CTR_OFF) + iter;
    atomicAdd(ctr, 1);
    while (atomicAdd(ctr, 0) < 4) { __builtin_amdgcn_s_sleep(1); }
  }
  __syncthreads();
  __threadfence();
  float HWn = (float)(HW - n);
#define LB(i) float lb1_##i = logf(HWn + ws[S1_OFF + iter * C + (i)]); \
              float lb2_##i = logf(HWn + ws[S2_OFF + iter * C + (i)]);
  REP21(LB)
#undef LB
  float* contb = ws + CONTB_OFF;
  for (int j = blockIdx.x * 256 + tid; j < n; j += 1024) {
    int p = list[j];
#define LQ2(i) float q##i = __expf(bf2f(qh[(size_t)(i) * HW + p]));
    REP21(LQ2)
#undef LQ2
    float s = ((((q0+q1)+(q2+q3))+((q4+q5)+(q6+q7)))+(((q8+q9)+(q10+q11))+((q12+q13)+(q14+q15))))+(((q16+q17)+(q18+q19))+q20);
    float inv = 1.f / s;
    float smax = 0.f;
#define NM2(i) q##i *= inv; smax = fmaxf(smax, q##i);
    REP21(NM2)
#undef NM2
#define CW(i) { float A = (q##i == smax) ? smax : q##i + smax; \
                float ft = lb1_##i / q##i; \
                float ft2 = lb2_##i / A; \
                contb[j * C + (i)] = loww[i] * ft + high0 * (1.f - ft) \
                                   + loww[C + (i)] * ft2 + high1 * (1.f - ft2); }
    REP21(CW)
#undef CW
  }
}

// softmax + channel-mix: bf16-pair q in, interleaved (t1|t2<<16) out.
__global__ __launch_bounds__(256) void k_smmix(const unsigned* __restrict__ q16x2,
                                               unsigned* __restrict__ t12,
                                               const float* __restrict__ ws) {
  int tid = threadIdx.x;
  int b2 = blockIdx.x * 256 + tid;   // pair index within channel
#define LQ(i) unsigned d##i = q16x2[(size_t)(i) * (HW/2) + b2]; \
              float ex##i = __expf(__uint_as_float(d##i << 16)); \
              float ey##i = __expf(__uint_as_float(d##i & 0xFFFF0000u));
  REP21(LQ)
#undef LQ
  float sa = ((((ex0+ex1)+(ex2+ex3))+((ex4+ex5)+(ex6+ex7)))+(((ex8+ex9)+(ex10+ex11))+((ex12+ex13)+(ex14+ex15))))+(((ex16+ex17)+(ex18+ex19))+ex20);
  float sb = ((((ey0+ey1)+(ey2+ey3))+((ey4+ey5)+(ey6+ey7)))+(((ey8+ey9)+(ey10+ey11))+((ey12+ey13)+(ey14+ey15))))+(((ey16+ey17)+(ey18+ey19))+ey20);
  float ia = 1.f / sa, ib = 1.f / sb;
#define NQ(i) ex##i *= ia; ey##i *= ib;
  REP21(NQ)
#undef NQ
  for (int i = 0; i < C; ++i) {
    const float* r1 = ws + M1_OFF + i * C;
    const float* r2 = ws + M2_OFF + i * C;
    float t1a = 0.f, t1b = 0.f, t2a = 0.f, t2b = 0.f;
#define MIX(c) { float m1v = r1[c], m2v = r2[c]; \
                 t1a += m1v * ex##c; t1b += m1v * ey##c; \
                 t2a += m2v * ex##c; t2b += m2v * ey##c; }
    REP21(MIX)
#undef MIX
    uint2 st;
    st.x = packbf(t1a, t2a);
    st.y = packbf(t1b, t2b);
    *reinterpret_cast<uint2*>(t12 + (size_t)i * HW + 2 * b2) = st;
  }
}

// fused 2D blur + norm + q-update. 128x16 tile, interleaved bf16 pair loads.
// Always writes packed bf16 q (C,H,W) via coalesced uint2 stores.
__global__ __launch_bounds__(256) void k_blur2d(
    const unsigned* __restrict__ t12, const unsigned* __restrict__ uh32,
    unsigned* __restrict__ qout, const float* __restrict__ ws,
    const float* __restrict__ highw) {
  __shared__ float asmem[16 * 152], bsmem[16 * 152];
  __shared__ float ktsp[KSP], ktbi[KBI];
  __shared__ float nspw[128], nbiw[128], nsph[16], nbih[16];
  int tid = threadIdx.x;
  // bijective XCD-chunk swizzle: 2688 blocks = 8 * 336
  int l = blockIdx.x;
  int nl = (l & 7) * 336 + (l >> 3);
  int c = nl >> 7;                 // 128 tiles per channel
  int rem = nl & 127;
  int h0 = (rem >> 2) * 16;
  int w0 = (rem & 3) * 128;
  if (tid < KSP) ktsp[tid] = ws[KSP_OFF + tid];
  if (tid >= 32 && tid < 32 + KBI) ktbi[tid - 32] = ws[KBI_OFF + tid - 32];
  if (tid >= 64 && tid < 192) {
    int i = tid - 64;
    nspw[i] = ws[NSP_OFF + w0 + i];
    nbiw[i] = ws[NBI_OFF + w0 + i];
  }
  if (tid >= 192 && tid < 208) {
    int i = tid - 192;
    nsph[i] = ws[NSP_OFF + h0 + i];
    nbih[i] = ws[NBI_OFF + h0 + i];
  }
  __syncthreads();
  size_t cbase = (size_t)c * HW;
  if (tid < 144) {
    int col = w0 - 8 + tid;
    bool okc = (col >= 0 && col < W);
    const unsigned* s12 = t12 + cbase;
    unsigned lv[32];
    SFOR(32, [&](auto jc) {
      constexpr int j = decltype(jc)::value;
      int hh = h0 - 8 + j;
      lv[j] = (okc && hh >= 0 && hh < H) ? s12[(size_t)hh * W + col] : 0u;
    });
    float a[16], b[16];
    SFOR(16, [&](auto oc) {
      constexpr int o = decltype(oc)::value;
      a[o] = 0.f; b[o] = 0.f;
    });
    SFOR(32, [&](auto jc) {
      constexpr int j = decltype(jc)::value;
      float f1 = __uint_as_float(lv[j] << 16);
      float f2 = __uint_as_float(lv[j] & 0xFFFF0000u);
      SFOR(16, [&](auto oc) {
        constexpr int o = decltype(oc)::value;
        if constexpr (j - 2 - o >= 0 && j - 2 - o < KSP) a[o] += ktsp[j - 2 - o] * f1;
        if constexpr (j - o >= 0 && j - o < KBI) b[o] += ktbi[j - o] * f2;
      });
    });
    SFOR(16, [&](auto oc) {
      constexpr int o = decltype(oc)::value;
      asmem[o * 152 + tid] = a[o];
      bsmem[o * 152 + tid] = b[o];
    });
  }
  __syncthreads();
  float cc = highw[0] + highw[1];
#pragma unroll
  for (int k = 0; k < 2; ++k) {
    int o = tid + k * 256;          // quad index, 512 quads (4 outputs each)
    int r = o >> 5;                 // 32 quads per row
    int wq = (o & 31) * 4;          // start col within tile (mult of 4)
    float aw[16], bw[20];
    const float2* ap = reinterpret_cast<const float2*>(&asmem[r * 152 + wq + 2]);
    const float2* bp = reinterpret_cast<const float2*>(&bsmem[r * 152 + wq]);
    SFOR(8, [&](auto jc) {
      constexpr int j = decltype(jc)::value;
      float2 v = ap[j];
      aw[2 * j] = v.x;
      aw[2 * j + 1] = v.y;
    });
    SFOR(10, [&](auto jc) {
      constexpr int j = decltype(jc)::value;
      float2 v = bp[j];
      bw[2 * j] = v.x;
      bw[2 * j + 1] = v.y;
    });
    float ao[4], bo[4];
    SFOR(4, [&](auto jc) {
      constexpr int j = decltype(jc)::value;
      float s1 = 0.f;
      float s2 = 0.f;
      SFOR(KSP, [&](auto tc) {
        constexpr int t = decltype(tc)::value;
        s1 += ktsp[t] * aw[j + t];
      });
      SFOR(KBI, [&](auto tc) {
        constexpr int t = decltype(tc)::value;
        s2 += ktbi[t] * bw[j + t];
      });
      ao[j] = s1;
      bo[j] = s2;
    });
    int hh = h0 + r, ww = w0 + wq;
    size_t idx = cbase + (size_t)hh * W + ww;
    uint2 uv = *reinterpret_cast<const uint2*>(uh32 + (idx >> 1));
    float u0 = __uint_as_float(uv.x << 16);
    float u1 = __uint_as_float(uv.x & 0xFFFF0000u);
    float u2 = __uint_as_float(uv.y << 16);
    float u3 = __uint_as_float(uv.y & 0xFFFF0000u);
    float nh1 = nsph[r], nh2 = nbih[r];
    float r0 = u0 - (ao[0] * (nh1 * nspw[wq])     + bo[0] * (nh2 * nbiw[wq]))     - cc;
    float r1 = u1 - (ao[1] * (nh1 * nspw[wq + 1]) + bo[1] * (nh2 * nbiw[wq + 1])) - cc;
    float r2 = u2 - (ao[2] * (nh1 * nspw[wq + 2]) + bo[2] * (nh2 * nbiw[wq + 2])) - cc;
    float r3 = u3 - (ao[3] * (nh1 * nspw[wq + 3]) + bo[3] * (nh2 * nbiw[wq + 3])) - cc;
    uint2 st;
    st.x = packbf(r0, r1);
    st.y = packbf(r2, r3);
    *reinterpret_cast<uint2*>(qout + (idx >> 1)) = st;
  }
}

// patch cond pixels in bf16 q: q += cc - cont
__global__ __launch_bounds__(256) void k_contfix(unsigned short* __restrict__ q16,
                                                 const float* __restrict__ ws,
                                                 const float* __restrict__ highw,
                                                 int iter) {
  const int* ncond = (const int*)(ws + NCOND_OFF);
  int n = ncond[iter]; if (n > LIST_CAP) n = LIST_CAP;
  int e = blockIdx.x * 256 + threadIdx.x;
  if (e >= n * C) return;
  int j = e / C, c = e - j * C;
  const int* list = (const int*)(ws + LIST_OFF) + iter * LIST_CAP;
  int p = list[j];
  float cc = highw[0] + highw[1];
  float delta = cc - ws[CONTB_OFF + e];
  size_t idx = (size_t)c * HW + p;
  q16[idx] = f2bfu(bf2f(q16[idx]) + delta);
}

extern "C" void kernel_launch(void* const* d_in, const int* in_sizes, int n_in,
                              void* d_out, int out_size, void* d_ws, size_t ws_size,
                              hipStream_t stream) {
  const float* unaries = (const float*)d_in[0];
  const int* sp_map = (const int*)d_in[2];
  const float* skw = (const float*)d_in[3];
  const float* bkw = (const float*)d_in[4];
  const float* loww = (const float*)d_in[5];
  const float* highw = (const float*)d_in[6];
  const float* cm = (const float*)d_in[7];
  float* out = (float*)d_out;
  float* ws = (float*)d_ws;
  unsigned* ubh32 = (unsigned*)(ws + UBH_OFF);
  unsigned* qb32 = (unsigned*)(ws + QB16_OFF);
  unsigned short* qh16 = (unsigned short*)(ws + QB16_OFF);
  const unsigned short* uh16 = (const unsigned short*)(ws + UBH_OFF);
  unsigned* t12 = (unsigned*)(ws + T12_OFF);
  int* ncond = (int*)(ws + NCOND_OFF);
  int* list = (int*)(ws + LIST_OFF);

  k_setup<<<1, 512, 0, stream>>>(ws, skw, bkw, cm);
  k_spt_tin<<<HW / 256, 256, 0, stream>>>(sp_map, unaries, ncond, list, ubh32);
  for (int i = 0; i < N_ITERS; ++i) {
    // iter 0 reads ubh directly (q0 == bf16(u))
    const unsigned short* qcur16 = (i == 0) ? uh16 : (const unsigned short*)qh16;
    const unsigned* qcur32 = (i == 0) ? ubh32 : qb32;
    k_clique<<<4, 256, 0, stream>>>(qcur16, ws, loww, highw, i);
    k_smmix<<<HW / 512, 256, 0, stream>>>(qcur32, t12, ws);
    k_blur2d<<<2688, 256, 0, stream>>>(t12, ubh32, qb32, ws, highw);
    k_contfix<<<128, 256, 0, stream>>>(qh16, ws, highw, i);
  }
  k_tout<<<HW / 256, 256, 0, stream>>>(qb32, out);
}

// Round 18
// 312.859 us; speedup vs baseline: 1.3283x; 1.1901x over previous
//
#include <hip/hip_runtime.h>
#include <hip/hip_bf16.h>
#include <math.h>
#include <utility>

#define C 21
#define H 512
#define W 512
#define HW (H*W)
#define CHW (C*HW)
#define N_ITERS 5
#define RSP 6
#define KSP 13
#define RBI 8
#define KBI 17
#define LIST_CAP 4096

// workspace layout (float offsets)
#define KSP_OFF   0
#define KBI_OFF   16
#define NSP_OFF   64      // stores 1/nsp
#define NBI_OFF   576     // stores 1/nbi
#define M1_OFF    1088
#define M2_OFF    1536
#define NCOND_OFF 2048    // N_ITERS ints
#define S1_OFF    2064    // N_ITERS*C
#define S2_OFF    2176    // N_ITERS*C
#define CTR_OFF   2288    // N_ITERS ints (spin-barrier counters)
#define LIST_OFF  2304    // N_ITERS*LIST_CAP ints -> ends 22784
#define CONTB_OFF 22784   // LIST_CAP*C floats -> ends 108800
#define UBH_OFF   131072                  // CHW bf16 = CHW/2 floats
#define QB16_OFF  (UBH_OFF + CHW/2)       // CHW bf16 (q iterate)
#define T12_OFF   (QB16_OFF + CHW/2)      // CHW dwords (bf16 t1 | t2<<16)

#define REP21(F) F(0) F(1) F(2) F(3) F(4) F(5) F(6) F(7) F(8) F(9) F(10) \
                 F(11) F(12) F(13) F(14) F(15) F(16) F(17) F(18) F(19) F(20)

template <int... Js, typename F>
__device__ __forceinline__ void sfor(std::integer_sequence<int, Js...>, F&& f) {
  (f(std::integral_constant<int, Js>{}), ...);
}
#define SFOR(N, ...) sfor(std::make_integer_sequence<int, N>{}, __VA_ARGS__)

__device__ __forceinline__ float bf2f(unsigned short u) {
  return __uint_as_float(((unsigned)u) << 16);
}
__device__ __forceinline__ unsigned short f2bfu(float a) {
  __hip_bfloat16 h = __float2bfloat16(a);
  return *(unsigned short*)&h;
}
__device__ __forceinline__ unsigned packbf(float a, float b) {
  return (unsigned)f2bfu(a) | ((unsigned)f2bfu(b) << 16);
}

__global__ __launch_bounds__(512) void k_setup(float* ws, const float* skw,
                                               const float* bkw, const float* cm) {
  int tid = threadIdx.x;
  if (tid == 0) {
    float s = 0.f;
    for (int i = 0; i < KSP; ++i) {
      float t = (float)(i - RSP);
      float v = expf(-0.5f * (t / 3.0f) * (t / 3.0f));
      ws[KSP_OFF + i] = v; s += v;
    }
    for (int i = 0; i < KSP; ++i) ws[KSP_OFF + i] /= s;
    s = 0.f;
    for (int i = 0; i < KBI; ++i) {
      float t = (float)(i - RBI);
      float v = expf(-0.5f * (t / 160.0f) * (t / 160.0f));
      ws[KBI_OFF + i] = v; s += v;
    }
    for (int i = 0; i < KBI; ++i) ws[KBI_OFF + i] /= s;
  }
  __syncthreads();
  if (tid < H) {
    float nsp = 0.f, nbi = 0.f;
    for (int t = 0; t < KSP; ++t) { int x = tid + t - RSP; if (x >= 0 && x < H) nsp += ws[KSP_OFF + t]; }
    for (int t = 0; t < KBI; ++t) { int x = tid + t - RBI; if (x >= 0 && x < H) nbi += ws[KBI_OFF + t]; }
    ws[NSP_OFF + tid] = 1.f / nsp;
    ws[NBI_OFF + tid] = 1.f / nbi;
  }
  if (tid < C * C) {
    int i = tid / C, j = tid % C;
    float m1 = 0.f, m2 = 0.f;
    for (int k = 0; k < C; ++k) {
      m1 += cm[i * C + k] * skw[k * C + j];
      m2 += cm[i * C + k] * bkw[k * C + j];
    }
    ws[M1_OFF + tid] = m1;
    ws[M2_OFF + tid] = m2;
  }
  if (tid < N_ITERS * C) { ws[S1_OFF + tid] = 0.f; ws[S2_OFF + tid] = 0.f; }
  if (tid < N_ITERS) {
    ((int*)(ws + NCOND_OFF))[tid] = 0;
    ((int*)(ws + CTR_OFF))[tid] = 0;
  }
}

// merged: compact per-sp_id pixel lists (coalesced sp_map read) +
// (H,W,C)f32 -> (C,H,W)bf16 u shadow. bf16-in-LDS, float4 global loads.
__global__ __launch_bounds__(256) void k_spt_tin(const int* __restrict__ sp_map,
                                                 const float* __restrict__ in,
                                                 int* __restrict__ ncond,
                                                 int* __restrict__ list,
                                                 unsigned* __restrict__ ubh32) {
  __shared__ unsigned short t16[C * 264];   // 264 = padded row (ushort)
  int tid = threadIdx.x;
  {
    int m = blockIdx.x * 256 + tid;      // coalesced index into sp_map (W,H)
    int v = sp_map[m];
    int p = ((m & 511) << 9) | (m >> 9); // pixel index in (H,W) space
#pragma unroll
    for (int i = 0; i < N_ITERS; ++i)
      if (v == 250 + 7 * i) {
        int slot = atomicAdd(&ncond[i], 1);
        if (slot < LIST_CAP) list[i * LIST_CAP + slot] = p;
      }
  }
  size_t p0 = (size_t)blockIdx.x * 256;
  const float4* in4 = (const float4*)(in + p0 * C);
  // C*256 = 5376 floats = 1344 float4
#pragma unroll
  for (int k = 0; k < 6; ++k) {
    int f = k * 256 + tid;
    if (k < 5 || f < 1344) {
      float4 v = in4[f];
      int e = 4 * f;
      int c0 = e % C, p_ = e / C;
      // 4 consecutive elements: c increments (mod C), p bumps on wrap
      int c = c0, pp = p_;
      t16[c * 264 + pp] = f2bfu(v.x);
      if (++c == C) { c = 0; ++pp; } t16[c * 264 + pp] = f2bfu(v.y);
      if (++c == C) { c = 0; ++pp; } t16[c * 264 + pp] = f2bfu(v.z);
      if (++c == C) { c = 0; ++pp; } t16[c * 264 + pp] = f2bfu(v.w);
    }
  }
  __syncthreads();
  // phase 2: pure dword copy LDS -> global, coalesced
  const unsigned* t32 = (const unsigned*)t16;  // dword row stride 132
  for (int e = tid; e < C * 128; e += 256) {
    int c = e >> 7, pr = e & 127;
    ubh32[((size_t)c * HW + p0) / 2 + pr] = t32[c * 132 + pr];
  }
}

// final transpose: (C,H,W) bf16 q -> (H,W,C) f32 out
__global__ __launch_bounds__(256) void k_tout(const unsigned* __restrict__ qb32,
                                              float* __restrict__ out) {
  __shared__ float t[C * 257];
  int tid = threadIdx.x;
  size_t p0 = (size_t)blockIdx.x * 256;
  if (tid < 128) {
#pragma unroll
    for (int c = 0; c < C; ++c) {
      unsigned d = qb32[((size_t)c * HW + p0) / 2 + tid];
      t[c * 257 + 2 * tid] = __uint_as_float(d << 16);
      t[c * 257 + 2 * tid + 1] = __uint_as_float(d & 0xFFFF0000u);
    }
  }
  __syncthreads();
  size_t fbase = p0 * C;
#pragma unroll
  for (int i = 0; i < C; ++i) {
    int e = i * 256 + tid;
    int p = e / C, c = e % C;
    out[fbase + e] = t[c * 257 + p];
  }
}

// fused clique + smmix. Blocks 0..3: clique (pass A -> 4-block spin barrier
// -> pass B). Blocks 4..515: softmax+channel-mix. Both read-only on q;
// disjoint outputs; all 516 blocks co-resident so the barrier is safe.
__global__ __launch_bounds__(256) void k_cliquemix(
    const unsigned short* __restrict__ qh, const unsigned* __restrict__ q16x2,
    unsigned* __restrict__ t12, float* __restrict__ ws,
    const float* __restrict__ loww, const float* __restrict__ highw, int iter) {
  int tid = threadIdx.x;
  if (blockIdx.x < 4) {
    const int* ncond = (const int*)(ws + NCOND_OFF);
    const int* list = (const int*)(ws + LIST_OFF) + iter * LIST_CAP;
    int n = ncond[iter]; if (n > LIST_CAP) n = LIST_CAP;
    float high0 = highw[0], high1 = highw[1];
#define D1(i) float s1_##i = 0.f, s2_##i = 0.f;
    REP21(D1)
#undef D1
    for (int j = blockIdx.x * 256 + tid; j < n; j += 1024) {
      int p = list[j];
#define LQ(i) float q##i = __expf(bf2f(qh[(size_t)(i) * HW + p]));
      REP21(LQ)
#undef LQ
      float s = ((((q0+q1)+(q2+q3))+((q4+q5)+(q6+q7)))+(((q8+q9)+(q10+q11))+((q12+q13)+(q14+q15))))+(((q16+q17)+(q18+q19))+q20);
      float inv = 1.f / s;
      float smax = 0.f;
#define NM(i) q##i *= inv; smax = fmaxf(smax, q##i);
      REP21(NM)
#undef NM
#define AC(i) { s1_##i += __expf(q##i); \
                float A = (q##i == smax) ? smax : q##i + smax; \
                s2_##i += __expf(A); }
      REP21(AC)
#undef AC
    }
#define RED(x) x += __shfl_xor(x, 32); x += __shfl_xor(x, 16); x += __shfl_xor(x, 8); \
               x += __shfl_xor(x, 4); x += __shfl_xor(x, 2); x += __shfl_xor(x, 1);
#define RD(i) RED(s1_##i) RED(s2_##i)
    REP21(RD)
#undef RD
#undef RED
    if ((tid & 63) == 0) {
#define AT(i) atomicAdd(&ws[S1_OFF + iter * C + (i)], s1_##i); \
              atomicAdd(&ws[S2_OFF + iter * C + (i)], s2_##i);
      REP21(AT)
#undef AT
    }
    __threadfence();
    __syncthreads();
    if (tid == 0) {
      int* ctr = (int*)(ws + CTR_OFF) + iter;
      atomicAdd(ctr, 1);
      while (atomicAdd(ctr, 0) < 4) { __builtin_amdgcn_s_sleep(1); }
    }
    __syncthreads();
    __threadfence();
    float HWn = (float)(HW - n);
#define LB(i) float lb1_##i = logf(HWn + ws[S1_OFF + iter * C + (i)]); \
              float lb2_##i = logf(HWn + ws[S2_OFF + iter * C + (i)]);
    REP21(LB)
#undef LB
    float* contb = ws + CONTB_OFF;
    for (int j = blockIdx.x * 256 + tid; j < n; j += 1024) {
      int p = list[j];
#define LQ2(i) float q##i = __expf(bf2f(qh[(size_t)(i) * HW + p]));
      REP21(LQ2)
#undef LQ2
      float s = ((((q0+q1)+(q2+q3))+((q4+q5)+(q6+q7)))+(((q8+q9)+(q10+q11))+((q12+q13)+(q14+q15))))+(((q16+q17)+(q18+q19))+q20);
      float inv = 1.f / s;
      float smax = 0.f;
#define NM2(i) q##i *= inv; smax = fmaxf(smax, q##i);
      REP21(NM2)
#undef NM2
#define CW(i) { float A = (q##i == smax) ? smax : q##i + smax; \
                float ft = lb1_##i / q##i; \
                float ft2 = lb2_##i / A; \
                contb[j * C + (i)] = loww[i] * ft + high0 * (1.f - ft) \
                                   + loww[C + (i)] * ft2 + high1 * (1.f - ft2); }
      REP21(CW)
#undef CW
    }
    return;
  }
  // smmix path
  int b2 = (blockIdx.x - 4) * 256 + tid;   // pair index within channel
#define LQS(i) unsigned d##i = q16x2[(size_t)(i) * (HW/2) + b2]; \
               float ex##i = __expf(__uint_as_float(d##i << 16)); \
               float ey##i = __expf(__uint_as_float(d##i & 0xFFFF0000u));
  REP21(LQS)
#undef LQS
  float sa = ((((ex0+ex1)+(ex2+ex3))+((ex4+ex5)+(ex6+ex7)))+(((ex8+ex9)+(ex10+ex11))+((ex12+ex13)+(ex14+ex15))))+(((ex16+ex17)+(ex18+ex19))+ex20);
  float sb = ((((ey0+ey1)+(ey2+ey3))+((ey4+ey5)+(ey6+ey7)))+(((ey8+ey9)+(ey10+ey11))+((ey12+ey13)+(ey14+ey15))))+(((ey16+ey17)+(ey18+ey19))+ey20);
  float ia = 1.f / sa, ib = 1.f / sb;
#define NQ(i) ex##i *= ia; ey##i *= ib;
  REP21(NQ)
#undef NQ
  for (int i = 0; i < C; ++i) {
    const float* r1 = ws + M1_OFF + i * C;
    const float* r2 = ws + M2_OFF + i * C;
    float t1a = 0.f, t1b = 0.f, t2a = 0.f, t2b = 0.f;
#define MIX(c) { float m1v = r1[c], m2v = r2[c]; \
                 t1a += m1v * ex##c; t1b += m1v * ey##c; \
                 t2a += m2v * ex##c; t2b += m2v * ey##c; }
    REP21(MIX)
#undef MIX
    uint2 st;
    st.x = packbf(t1a, t2a);
    st.y = packbf(t1b, t2b);
    *reinterpret_cast<uint2*>(t12 + (size_t)i * HW + 2 * b2) = st;
  }
}

// fused 2D blur + norm + q-update. 128x16 tile, interleaved bf16 pair loads.
// Always writes packed bf16 q (C,H,W) via coalesced uint2 stores.
__global__ __launch_bounds__(256) void k_blur2d(
    const unsigned* __restrict__ t12, const unsigned* __restrict__ uh32,
    unsigned* __restrict__ qout, const float* __restrict__ ws,
    const float* __restrict__ highw) {
  __shared__ float asmem[16 * 152], bsmem[16 * 152];
  __shared__ float ktsp[KSP], ktbi[KBI];
  __shared__ float nspw[128], nbiw[128], nsph[16], nbih[16];
  int tid = threadIdx.x;
  // bijective XCD-chunk swizzle: 2688 blocks = 8 * 336
  int l = blockIdx.x;
  int nl = (l & 7) * 336 + (l >> 3);
  int c = nl >> 7;                 // 128 tiles per channel
  int rem = nl & 127;
  int h0 = (rem >> 2) * 16;
  int w0 = (rem & 3) * 128;
  if (tid < KSP) ktsp[tid] = ws[KSP_OFF + tid];
  if (tid >= 32 && tid < 32 + KBI) ktbi[tid - 32] = ws[KBI_OFF + tid - 32];
  if (tid >= 64 && tid < 192) {
    int i = tid - 64;
    nspw[i] = ws[NSP_OFF + w0 + i];
    nbiw[i] = ws[NBI_OFF + w0 + i];
  }
  if (tid >= 192 && tid < 208) {
    int i = tid - 192;
    nsph[i] = ws[NSP_OFF + h0 + i];
    nbih[i] = ws[NBI_OFF + h0 + i];
  }
  __syncthreads();
  size_t cbase = (size_t)c * HW;
  if (tid < 144) {
    int col = w0 - 8 + tid;
    bool okc = (col >= 0 && col < W);
    const unsigned* s12 = t12 + cbase;
    unsigned lv[32];
    SFOR(32, [&](auto jc) {
      constexpr int j = decltype(jc)::value;
      int hh = h0 - 8 + j;
      lv[j] = (okc && hh >= 0 && hh < H) ? s12[(size_t)hh * W + col] : 0u;
    });
    float a[16], b[16];
    SFOR(16, [&](auto oc) {
      constexpr int o = decltype(oc)::value;
      a[o] = 0.f; b[o] = 0.f;
    });
    SFOR(32, [&](auto jc) {
      constexpr int j = decltype(jc)::value;
      float f1 = __uint_as_float(lv[j] << 16);
      float f2 = __uint_as_float(lv[j] & 0xFFFF0000u);
      SFOR(16, [&](auto oc) {
        constexpr int o = decltype(oc)::value;
        if constexpr (j - 2 - o >= 0 && j - 2 - o < KSP) a[o] += ktsp[j - 2 - o] * f1;
        if constexpr (j - o >= 0 && j - o < KBI) b[o] += ktbi[j - o] * f2;
      });
    });
    SFOR(16, [&](auto oc) {
      constexpr int o = decltype(oc)::value;
      asmem[o * 152 + tid] = a[o];
      bsmem[o * 152 + tid] = b[o];
    });
  }
  __syncthreads();
  float cc = highw[0] + highw[1];
#pragma unroll
  for (int k = 0; k < 2; ++k) {
    int o = tid + k * 256;          // quad index, 512 quads (4 outputs each)
    int r = o >> 5;                 // 32 quads per row
    int wq = (o & 31) * 4;          // start col within tile (mult of 4)
    float aw[16], bw[20];
    const float2* ap = reinterpret_cast<const float2*>(&asmem[r * 152 + wq + 2]);
    const float2* bp = reinterpret_cast<const float2*>(&bsmem[r * 152 + wq]);
    SFOR(8, [&](auto jc) {
      constexpr int j = decltype(jc)::value;
      float2 v = ap[j];
      aw[2 * j] = v.x;
      aw[2 * j + 1] = v.y;
    });
    SFOR(10, [&](auto jc) {
      constexpr int j = decltype(jc)::value;
      float2 v = bp[j];
      bw[2 * j] = v.x;
      bw[2 * j + 1] = v.y;
    });
    float ao[4], bo[4];
    SFOR(4, [&](auto jc) {
      constexpr int j = decltype(jc)::value;
      float s1 = 0.f;
      float s2 = 0.f;
      SFOR(KSP, [&](auto tc) {
        constexpr int t = decltype(tc)::value;
        s1 += ktsp[t] * aw[j + t];
      });
      SFOR(KBI, [&](auto tc) {
        constexpr int t = decltype(tc)::value;
        s2 += ktbi[t] * bw[j + t];
      });
      ao[j] = s1;
      bo[j] = s2;
    });
    int hh = h0 + r, ww = w0 + wq;
    size_t idx = cbase + (size_t)hh * W + ww;
    uint2 uv = *reinterpret_cast<const uint2*>(uh32 + (idx >> 1));
    float u0 = __uint_as_float(uv.x << 16);
    float u1 = __uint_as_float(uv.x & 0xFFFF0000u);
    float u2 = __uint_as_float(uv.y << 16);
    float u3 = __uint_as_float(uv.y & 0xFFFF0000u);
    float nh1 = nsph[r], nh2 = nbih[r];
    float r0 = u0 - (ao[0] * (nh1 * nspw[wq])     + bo[0] * (nh2 * nbiw[wq]))     - cc;
    float r1 = u1 - (ao[1] * (nh1 * nspw[wq + 1]) + bo[1] * (nh2 * nbiw[wq + 1])) - cc;
    float r2 = u2 - (ao[2] * (nh1 * nspw[wq + 2]) + bo[2] * (nh2 * nbiw[wq + 2])) - cc;
    float r3 = u3 - (ao[3] * (nh1 * nspw[wq + 3]) + bo[3] * (nh2 * nbiw[wq + 3])) - cc;
    uint2 st;
    st.x = packbf(r0, r1);
    st.y = packbf(r2, r3);
    *reinterpret_cast<uint2*>(qout + (idx >> 1)) = st;
  }
}

// patch cond pixels in bf16 q: q += cc - cont
__global__ __launch_bounds__(256) void k_contfix(unsigned short* __restrict__ q16,
                                                 const float* __restrict__ ws,
                                                 const float* __restrict__ highw,
                                                 int iter) {
  const int* ncond = (const int*)(ws + NCOND_OFF);
  int n = ncond[iter]; if (n > LIST_CAP) n = LIST_CAP;
  int e = blockIdx.x * 256 + threadIdx.x;
  if (e >= n * C) return;
  int j = e / C, c = e - j * C;
  const int* list = (const int*)(ws + LIST_OFF) + iter * LIST_CAP;
  int p = list[j];
  float cc = highw[0] + highw[1];
  float delta = cc - ws[CONTB_OFF + e];
  size_t idx = (size_t)c * HW + p;
  q16[idx] = f2bfu(bf2f(q16[idx]) + delta);
}

extern "C" void kernel_launch(void* const* d_in, const int* in_sizes, int n_in,
                              void* d_out, int out_size, void* d_ws, size_t ws_size,
                              hipStream_t stream) {
  const float* unaries = (const float*)d_in[0];
  const int* sp_map = (const int*)d_in[2];
  const float* skw = (const float*)d_in[3];
  const float* bkw = (const float*)d_in[4];
  const float* loww = (const float*)d_in[5];
  const float* highw = (const float*)d_in[6];
  const float* cm = (const float*)d_in[7];
  float* out = (float*)d_out;
  float* ws = (float*)d_ws;
  unsigned* ubh32 = (unsigned*)(ws + UBH_OFF);
  unsigned* qb32 = (unsigned*)(ws + QB16_OFF);
  unsigned short* qh16 = (unsigned short*)(ws + QB16_OFF);
  const unsigned short* uh16 = (const unsigned short*)(ws + UBH_OFF);
  unsigned* t12 = (unsigned*)(ws + T12_OFF);
  int* ncond = (int*)(ws + NCOND_OFF);
  int* list = (int*)(ws + LIST_OFF);

  k_setup<<<1, 512, 0, stream>>>(ws, skw, bkw, cm);
  k_spt_tin<<<HW / 256, 256, 0, stream>>>(sp_map, unaries, ncond, list, ubh32);
  for (int i = 0; i < N_ITERS; ++i) {
    // iter 0 reads ubh directly (q0 == bf16(u))
    const unsigned short* qcur16 = (i == 0) ? uh16 : (const unsigned short*)qh16;
    const unsigned* qcur32 = (i == 0) ? ubh32 : qb32;
    k_cliquemix<<<4 + HW / 512, 256, 0, stream>>>(qcur16, qcur32, t12, ws,
                                                  loww, highw, i);
    k_blur2d<<<2688, 256, 0, stream>>>(t12, ubh32, qb32, ws, highw);
    k_contfix<<<128, 256, 0, stream>>>(qh16, ws, highw, i);
  }
  k_tout<<<HW / 256, 256, 0, stream>>>(qb32, out);
}

// Round 20
// 311.203 us; speedup vs baseline: 1.3353x; 1.0053x over previous
//
#include <hip/hip_runtime.h>
#include <hip/hip_bf16.h>
#include <math.h>
#include <utility>

#define C 21
#define H 512
#define W 512
#define HW (H*W)
#define CHW (C*HW)
#define N_ITERS 5
#define RSP 6
#define KSP 13
#define RBI 8
#define KBI 17
#define LIST_CAP 4096

// workspace layout (float offsets)
#define KSP_OFF   0
#define KBI_OFF   16
#define NSP_OFF   64      // stores 1/nsp
#define NBI_OFF   576     // stores 1/nbi
#define M1_OFF    1088
#define M2_OFF    1536
#define NCOND_OFF 2048    // N_ITERS ints
#define S1_OFF    2064    // N_ITERS*C
#define S2_OFF    2176    // N_ITERS*C
#define CTR_OFF   2288    // N_ITERS ints (spin-barrier counters)
#define LIST_OFF  2304    // N_ITERS*LIST_CAP ints -> ends 22784
#define CONTB_OFF 22784   // LIST_CAP*C floats -> ends 108800
#define UBH_OFF   131072                  // CHW bf16 = CHW/2 floats
#define QB16_OFF  (UBH_OFF + CHW/2)       // CHW bf16 (q iterate)
#define T12_OFF   (QB16_OFF + CHW/2)      // CHW dwords (bf16 t1 | t2<<16)

#define REP21(F) F(0) F(1) F(2) F(3) F(4) F(5) F(6) F(7) F(8) F(9) F(10) \
                 F(11) F(12) F(13) F(14) F(15) F(16) F(17) F(18) F(19) F(20)

template <int... Js, typename F>
__device__ __forceinline__ void sfor(std::integer_sequence<int, Js...>, F&& f) {
  (f(std::integral_constant<int, Js>{}), ...);
}
#define SFOR(N, ...) sfor(std::make_integer_sequence<int, N>{}, __VA_ARGS__)

__device__ __forceinline__ float bf2f(unsigned short u) {
  return __uint_as_float(((unsigned)u) << 16);
}
__device__ __forceinline__ unsigned short f2bfu(float a) {
  __hip_bfloat16 h = __float2bfloat16(a);
  return *(unsigned short*)&h;
}
__device__ __forceinline__ unsigned packbf(float a, float b) {
  return (unsigned)f2bfu(a) | ((unsigned)f2bfu(b) << 16);
}

__global__ __launch_bounds__(512) void k_setup(float* ws, const float* skw,
                                               const float* bkw, const float* cm) {
  int tid = threadIdx.x;
  if (tid == 0) {
    float s = 0.f;
    for (int i = 0; i < KSP; ++i) {
      float t = (float)(i - RSP);
      float v = expf(-0.5f * (t / 3.0f) * (t / 3.0f));
      ws[KSP_OFF + i] = v; s += v;
    }
    for (int i = 0; i < KSP; ++i) ws[KSP_OFF + i] /= s;
    s = 0.f;
    for (int i = 0; i < KBI; ++i) {
      float t = (float)(i - RBI);
      float v = expf(-0.5f * (t / 160.0f) * (t / 160.0f));
      ws[KBI_OFF + i] = v; s += v;
    }
    for (int i = 0; i < KBI; ++i) ws[KBI_OFF + i] /= s;
  }
  __syncthreads();
  if (tid < H) {
    float nsp = 0.f, nbi = 0.f;
    for (int t = 0; t < KSP; ++t) { int x = tid + t - RSP; if (x >= 0 && x < H) nsp += ws[KSP_OFF + t]; }
    for (int t = 0; t < KBI; ++t) { int x = tid + t - RBI; if (x >= 0 && x < H) nbi += ws[KBI_OFF + t]; }
    ws[NSP_OFF + tid] = 1.f / nsp;
    ws[NBI_OFF + tid] = 1.f / nbi;
  }
  if (tid < C * C) {
    int i = tid / C, j = tid % C;
    float m1 = 0.f, m2 = 0.f;
    for (int k = 0; k < C; ++k) {
      m1 += cm[i * C + k] * skw[k * C + j];
      m2 += cm[i * C + k] * bkw[k * C + j];
    }
    ws[M1_OFF + tid] = m1;
    ws[M2_OFF + tid] = m2;
  }
  if (tid < N_ITERS * C) { ws[S1_OFF + tid] = 0.f; ws[S2_OFF + tid] = 0.f; }
  if (tid < N_ITERS) {
    ((int*)(ws + NCOND_OFF))[tid] = 0;
    ((int*)(ws + CTR_OFF))[tid] = 0;
  }
}

// merged: compact per-sp_id pixel lists (coalesced sp_map read) +
// (H,W,C)f32 -> (C,H,W)bf16 u shadow. 512 pixels/block, 11 upfront float4
// loads per thread for deep MLP.
__global__ __launch_bounds__(256) void k_spt_tin(const int* __restrict__ sp_map,
                                                 const float* __restrict__ in,
                                                 int* __restrict__ ncond,
                                                 int* __restrict__ list,
                                                 unsigned* __restrict__ ubh32) {
  __shared__ unsigned short t16[C * 528];   // 528 = padded row (ushort), 2 tiles
  int tid = threadIdx.x;
#pragma unroll
  for (int s = 0; s < 2; ++s) {
    int m = blockIdx.x * 512 + s * 256 + tid;   // coalesced index into sp_map
    int v = sp_map[m];
    int p = ((m & 511) << 9) | (m >> 9);        // pixel index in (H,W) space
#pragma unroll
    for (int i = 0; i < N_ITERS; ++i)
      if (v == 250 + 7 * i) {
        int slot = atomicAdd(&ncond[i], 1);
        if (slot < LIST_CAP) list[i * LIST_CAP + slot] = p;
      }
  }
  size_t p0 = (size_t)blockIdx.x * 512;
  const float4* in4 = (const float4*)(in + p0 * C);
  // C*512 = 10752 floats = 2688 float4; 10 full rounds + half round
  float4 lv[11];
  SFOR(11, [&](auto kc) {
    constexpr int k = decltype(kc)::value;
    if (k < 10 || tid < 128) lv[k] = in4[k * 256 + tid];
  });
  SFOR(11, [&](auto kc) {
    constexpr int k = decltype(kc)::value;
    if (k < 10 || tid < 128) {
      int e = 4 * (k * 256 + tid);
      int c = e % C, pp = e / C;
      t16[c * 528 + pp] = f2bfu(lv[k].x);
      if (++c == C) { c = 0; ++pp; } t16[c * 528 + pp] = f2bfu(lv[k].y);
      if (++c == C) { c = 0; ++pp; } t16[c * 528 + pp] = f2bfu(lv[k].z);
      if (++c == C) { c = 0; ++pp; } t16[c * 528 + pp] = f2bfu(lv[k].w);
    }
  });
  __syncthreads();
  // phase 2: pure dword copy LDS -> global, coalesced; 21 iterations
  const unsigned* t32 = (const unsigned*)t16;  // dword row stride 264
  for (int e = tid; e < C * 256; e += 256) {
    int c = e >> 8, pr = e & 255;
    ubh32[(size_t)c * (HW / 2) + p0 / 2 + pr] = t32[c * 264 + pr];
  }
}

// final transpose: (C,H,W) bf16 q -> (H,W,C) f32 out. 512 pixels/block,
// 21 upfront dword loads, packed-dword LDS.
__global__ __launch_bounds__(256) void k_tout(const unsigned* __restrict__ qb32,
                                              float* __restrict__ out) {
  __shared__ unsigned t32[C * 264];
  int tid = threadIdx.x;
  size_t p0 = (size_t)blockIdx.x * 512;
  unsigned lv[21];
  SFOR(21, [&](auto cc) {
    constexpr int c = decltype(cc)::value;
    lv[c] = qb32[(size_t)c * (HW / 2) + p0 / 2 + tid];
  });
  SFOR(21, [&](auto cc) {
    constexpr int c = decltype(cc)::value;
    t32[c * 264 + tid] = lv[c];
  });
  __syncthreads();
  float* outp = out + p0 * C;
  for (int e = tid; e < 512 * C; e += 256) {
    int p = e / C, c = e - p * C;
    unsigned d = t32[c * 264 + (p >> 1)];
    outp[e] = __uint_as_float((p & 1) ? (d & 0xFFFF0000u) : (d << 16));
  }
}

// fused clique + smmix. Blocks 0..3: clique (pass A -> 4-block spin barrier
// -> pass B). Blocks 4..515: softmax+channel-mix. Both read-only on q;
// disjoint outputs; all 516 blocks co-resident so the barrier is safe.
__global__ __launch_bounds__(256) void k_cliquemix(
    const unsigned short* __restrict__ qh, const unsigned* __restrict__ q16x2,
    unsigned* __restrict__ t12, float* __restrict__ ws,
    const float* __restrict__ loww, const float* __restrict__ highw, int iter) {
  int tid = threadIdx.x;
  if (blockIdx.x < 4) {
    const int* ncond = (const int*)(ws + NCOND_OFF);
    const int* list = (const int*)(ws + LIST_OFF) + iter * LIST_CAP;
    int n = ncond[iter]; if (n > LIST_CAP) n = LIST_CAP;
    float high0 = highw[0], high1 = highw[1];
#define D1(i) float s1_##i = 0.f, s2_##i = 0.f;
    REP21(D1)
#undef D1
    for (int j = blockIdx.x * 256 + tid; j < n; j += 1024) {
      int p = list[j];
#define LQ(i) float q##i = __expf(bf2f(qh[(size_t)(i) * HW + p]));
      REP21(LQ)
#undef LQ
      float s = ((((q0+q1)+(q2+q3))+((q4+q5)+(q6+q7)))+(((q8+q9)+(q10+q11))+((q12+q13)+(q14+q15))))+(((q16+q17)+(q18+q19))+q20);
      float inv = 1.f / s;
      float smax = 0.f;
#define NM(i) q##i *= inv; smax = fmaxf(smax, q##i);
      REP21(NM)
#undef NM
#define AC(i) { s1_##i += __expf(q##i); \
                float A = (q##i == smax) ? smax : q##i + smax; \
                s2_##i += __expf(A); }
      REP21(AC)
#undef AC
    }
#define RED(x) x += __shfl_xor(x, 32); x += __shfl_xor(x, 16); x += __shfl_xor(x, 8); \
               x += __shfl_xor(x, 4); x += __shfl_xor(x, 2); x += __shfl_xor(x, 1);
#define RD(i) RED(s1_##i) RED(s2_##i)
    REP21(RD)
#undef RD
#undef RED
    if ((tid & 63) == 0) {
#define AT(i) atomicAdd(&ws[S1_OFF + iter * C + (i)], s1_##i); \
              atomicAdd(&ws[S2_OFF + iter * C + (i)], s2_##i);
      REP21(AT)
#undef AT
    }
    __threadfence();
    __syncthreads();
    if (tid == 0) {
      int* ctr = (int*)(ws + CTR_OFF) + iter;
      atomicAdd(ctr, 1);
      while (atomicAdd(ctr, 0) < 4) { __builtin_amdgcn_s_sleep(1); }
    }
    __syncthreads();
    __threadfence();
    float HWn = (float)(HW - n);
#define LB(i) float lb1_##i = logf(HWn + ws[S1_OFF + iter * C + (i)]); \
              float lb2_##i = logf(HWn + ws[S2_OFF + iter * C + (i)]);
    REP21(LB)
#undef LB
    float* contb = ws + CONTB_OFF;
    for (int j = blockIdx.x * 256 + tid; j < n; j += 1024) {
      int p = list[j];
#define LQ2(i) float q##i = __expf(bf2f(qh[(size_t)(i) * HW + p]));
      REP21(LQ2)
#undef LQ2
      float s = ((((q0+q1)+(q2+q3))+((q4+q5)+(q6+q7)))+(((q8+q9)+(q10+q11))+((q12+q13)+(q14+q15))))+(((q16+q17)+(q18+q19))+q20);
      float inv = 1.f / s;
      float smax = 0.f;
#define NM2(i) q##i *= inv; smax = fmaxf(smax, q##i);
      REP21(NM2)
#undef NM2
#define CW(i) { float A = (q##i == smax) ? smax : q##i + smax; \
                float ft = lb1_##i / q##i; \
                float ft2 = lb2_##i / A; \
                contb[j * C + (i)] = loww[i] * ft + high0 * (1.f - ft) \
                                   + loww[C + (i)] * ft2 + high1 * (1.f - ft2); }
      REP21(CW)
#undef CW
    }
    return;
  }
  // smmix path
  int b2 = (blockIdx.x - 4) * 256 + tid;   // pair index within channel
#define LQS(i) unsigned d##i = q16x2[(size_t)(i) * (HW/2) + b2]; \
               float ex##i = __expf(__uint_as_float(d##i << 16)); \
               float ey##i = __expf(__uint_as_float(d##i & 0xFFFF0000u));
  REP21(LQS)
#undef LQS
  float sa = ((((ex0+ex1)+(ex2+ex3))+((ex4+ex5)+(ex6+ex7)))+(((ex8+ex9)+(ex10+ex11))+((ex12+ex13)+(ex14+ex15))))+(((ex16+ex17)+(ex18+ex19))+ex20);
  float sb = ((((ey0+ey1)+(ey2+ey3))+((ey4+ey5)+(ey6+ey7)))+(((ey8+ey9)+(ey10+ey11))+((ey12+ey13)+(ey14+ey15))))+(((ey16+ey17)+(ey18+ey19))+ey20);
  float ia = 1.f / sa, ib = 1.f / sb;
#define NQ(i) ex##i *= ia; ey##i *= ib;
  REP21(NQ)
#undef NQ
  for (int i = 0; i < C; ++i) {
    const float* r1 = ws + M1_OFF + i * C;
    const float* r2 = ws + M2_OFF + i * C;
    float t1a = 0.f, t1b = 0.f, t2a = 0.f, t2b = 0.f;
#define MIX(c) { float m1v = r1[c], m2v = r2[c]; \
                 t1a += m1v * ex##c; t1b += m1v * ey##c; \
                 t2a += m2v * ex##c; t2b += m2v * ey##c; }
    REP21(MIX)
#undef MIX
    uint2 st;
    st.x = packbf(t1a, t2a);
    st.y = packbf(t1b, t2b);
    *reinterpret_cast<uint2*>(t12 + (size_t)i * HW + 2 * b2) = st;
  }
}

// fused 2D blur + norm + q-update. 128x16 tile, interleaved bf16 pair loads.
// Always writes packed bf16 q (C,H,W) via coalesced uint2 stores.
__global__ __launch_bounds__(256) void k_blur2d(
    const unsigned* __restrict__ t12, const unsigned* __restrict__ uh32,
    unsigned* __restrict__ qout, const float* __restrict__ ws,
    const float* __restrict__ highw) {
  __shared__ float asmem[16 * 152], bsmem[16 * 152];
  __shared__ float ktsp[KSP], ktbi[KBI];
  __shared__ float nspw[128], nbiw[128], nsph[16], nbih[16];
  int tid = threadIdx.x;
  // bijective XCD-chunk swizzle: 2688 blocks = 8 * 336
  int l = blockIdx.x;
  int nl = (l & 7) * 336 + (l >> 3);
  int c = nl >> 7;                 // 128 tiles per channel
  int rem = nl & 127;
  int h0 = (rem >> 2) * 16;
  int w0 = (rem & 3) * 128;
  if (tid < KSP) ktsp[tid] = ws[KSP_OFF + tid];
  if (tid >= 32 && tid < 32 + KBI) ktbi[tid - 32] = ws[KBI_OFF + tid - 32];
  if (tid >= 64 && tid < 192) {
    int i = tid - 64;
    nspw[i] = ws[NSP_OFF + w0 + i];
    nbiw[i] = ws[NBI_OFF + w0 + i];
  }
  if (tid >= 192 && tid < 208) {
    int i = tid - 192;
    nsph[i] = ws[NSP_OFF + h0 + i];
    nbih[i] = ws[NBI_OFF + h0 + i];
  }
  __syncthreads();
  size_t cbase = (size_t)c * HW;
  if (tid < 144) {
    int col = w0 - 8 + tid;
    bool okc = (col >= 0 && col < W);
    const unsigned* s12 = t12 + cbase;
    unsigned lv[32];
    SFOR(32, [&](auto jc) {
      constexpr int j = decltype(jc)::value;
      int hh = h0 - 8 + j;
      lv[j] = (okc && hh >= 0 && hh < H) ? s12[(size_t)hh * W + col] : 0u;
    });
    float a[16], b[16];
    SFOR(16, [&](auto oc) {
      constexpr int o = decltype(oc)::value;
      a[o] = 0.f; b[o] = 0.f;
    });
    SFOR(32, [&](auto jc) {
      constexpr int j = decltype(jc)::value;
      float f1 = __uint_as_float(lv[j] << 16);
      float f2 = __uint_as_float(lv[j] & 0xFFFF0000u);
      SFOR(16, [&](auto oc) {
        constexpr int o = decltype(oc)::value;
        if constexpr (j - 2 - o >= 0 && j - 2 - o < KSP) a[o] += ktsp[j - 2 - o] * f1;
        if constexpr (j - o >= 0 && j - o < KBI) b[o] += ktbi[j - o] * f2;
      });
    });
    SFOR(16, [&](auto oc) {
      constexpr int o = decltype(oc)::value;
      asmem[o * 152 + tid] = a[o];
      bsmem[o * 152 + tid] = b[o];
    });
  }
  __syncthreads();
  float cc = highw[0] + highw[1];
#pragma unroll
  for (int k = 0; k < 2; ++k) {
    int o = tid + k * 256;          // quad index, 512 quads (4 outputs each)
    int r = o >> 5;                 // 32 quads per row
    int wq = (o & 31) * 4;          // start col within tile (mult of 4)
    float aw[16], bw[20];
    const float2* ap = reinterpret_cast<const float2*>(&asmem[r * 152 + wq + 2]);
    const float2* bp = reinterpret_cast<const float2*>(&bsmem[r * 152 + wq]);
    SFOR(8, [&](auto jc) {
      constexpr int j = decltype(jc)::value;
      float2 v = ap[j];
      aw[2 * j] = v.x;
      aw[2 * j + 1] = v.y;
    });
    SFOR(10, [&](auto jc) {
      constexpr int j = decltype(jc)::value;
      float2 v = bp[j];
      bw[2 * j] = v.x;
      bw[2 * j + 1] = v.y;
    });
    float ao[4], bo[4];
    SFOR(4, [&](auto jc) {
      constexpr int j = decltype(jc)::value;
      float s1 = 0.f;
      float s2 = 0.f;
      SFOR(KSP, [&](auto tc) {
        constexpr int t = decltype(tc)::value;
        s1 += ktsp[t] * aw[j + t];
      });
      SFOR(KBI, [&](auto tc) {
        constexpr int t = decltype(tc)::value;
        s2 += ktbi[t] * bw[j + t];
      });
      ao[j] = s1;
      bo[j] = s2;
    });
    int hh = h0 + r, ww = w0 + wq;
    size_t idx = cbase + (size_t)hh * W + ww;
    uint2 uv = *reinterpret_cast<const uint2*>(uh32 + (idx >> 1));
    float u0 = __uint_as_float(uv.x << 16);
    float u1 = __uint_as_float(uv.x & 0xFFFF0000u);
    float u2 = __uint_as_float(uv.y << 16);
    float u3 = __uint_as_float(uv.y & 0xFFFF0000u);
    float nh1 = nsph[r], nh2 = nbih[r];
    float r0 = u0 - (ao[0] * (nh1 * nspw[wq])     + bo[0] * (nh2 * nbiw[wq]))     - cc;
    float r1 = u1 - (ao[1] * (nh1 * nspw[wq + 1]) + bo[1] * (nh2 * nbiw[wq + 1])) - cc;
    float r2 = u2 - (ao[2] * (nh1 * nspw[wq + 2]) + bo[2] * (nh2 * nbiw[wq + 2])) - cc;
    float r3 = u3 - (ao[3] * (nh1 * nspw[wq + 3]) + bo[3] * (nh2 * nbiw[wq + 3])) - cc;
    uint2 st;
    st.x = packbf(r0, r1);
    st.y = packbf(r2, r3);
    *reinterpret_cast<uint2*>(qout + (idx >> 1)) = st;
  }
}

// patch cond pixels in bf16 q: q += cc - cont
__global__ __launch_bounds__(256) void k_contfix(unsigned short* __restrict__ q16,
                                                 const float* __restrict__ ws,
                                                 const float* __restrict__ highw,
                                                 int iter) {
  const int* ncond = (const int*)(ws + NCOND_OFF);
  int n = ncond[iter]; if (n > LIST_CAP) n = LIST_CAP;
  int e = blockIdx.x * 256 + threadIdx.x;
  if (e >= n * C) return;
  int j = e / C, c = e - j * C;
  const int* list = (const int*)(ws + LIST_OFF) + iter * LIST_CAP;
  int p = list[j];
  float cc = highw[0] + highw[1];
  float delta = cc - ws[CONTB_OFF + e];
  size_t idx = (size_t)c * HW + p;
  q16[idx] = f2bfu(bf2f(q16[idx]) + delta);
}

extern "C" void kernel_launch(void* const* d_in, const int* in_sizes, int n_in,
                              void* d_out, int out_size, void* d_ws, size_t ws_size,
                              hipStream_t stream) {
  const float* unaries = (const float*)d_in[0];
  const int* sp_map = (const int*)d_in[2];
  const float* skw = (const float*)d_in[3];
  const float* bkw = (const float*)d_in[4];
  const float* loww = (const float*)d_in[5];
  const float* highw = (const float*)d_in[6];
  const float* cm = (const float*)d_in[7];
  float* out = (float*)d_out;
  float* ws = (float*)d_ws;
  unsigned* ubh32 = (unsigned*)(ws + UBH_OFF);
  unsigned* qb32 = (unsigned*)(ws + QB16_OFF);
  unsigned short* qh16 = (unsigned short*)(ws + QB16_OFF);
  const unsigned short* uh16 = (const unsigned short*)(ws + UBH_OFF);
  unsigned* t12 = (unsigned*)(ws + T12_OFF);
  int* ncond = (int*)(ws + NCOND_OFF);
  int* list = (int*)(ws + LIST_OFF);

  k_setup<<<1, 512, 0, stream>>>(ws, skw, bkw, cm);
  k_spt_tin<<<HW / 512, 256, 0, stream>>>(sp_map, unaries, ncond, list, ubh32);
  for (int i = 0; i < N_ITERS; ++i) {
    // iter 0 reads ubh directly (q0 == bf16(u))
    const unsigned short* qcur16 = (i == 0) ? uh16 : (const unsigned short*)qh16;
    const unsigned* qcur32 = (i == 0) ? ubh32 : qb32;
    k_cliquemix<<<4 + HW / 512, 256, 0, stream>>>(qcur16, qcur32, t12, ws,
                                                  loww, highw, i);
    k_blur2d<<<2688, 256, 0, stream>>>(t12, ubh32, qb32, ws, highw);
    k_contfix<<<128, 256, 0, stream>>>(qh16, ws, highw, i);
  }
  k_tout<<<HW / 512, 256, 0, stream>>>(qb32, out);
}